// Round 9
// baseline (110.473 us; speedup 1.0000x reference)
//
#include <hip/hip_runtime.h>

// GAT layer, B=4, N=256, IN=128, H=4, D=64 — ONE plain launch, two phases,
// manual device-scope grid barrier (R16).
//
// Phase 1 (block = b,nt,ms): Wh^T bf16 tile + f1/f2 (MFMA fold, R8-verified)
//   -> workspace.  Ticket barrier (all 256 blocks co-resident: 256 thr,
//   ~30KB LDS, 1 block/CU guaranteed).  Phase 2 (same block = b,hp=nt,it=ms):
//   masked softmax (adj prefetched pre-barrier into registers) + K=256 MFMA
//   GEMM with ones-rowsum denominator (R6-verified).
//
// R9 rationale: R6=64.1 best; kernel-side ~24us = 2 dispatch boundaries +
// cold-start serialization. R5 (cooperative: +38) and R7 (recompute: +5.3)
// both failed; this keeps R6's exact work split and removes the boundary
// with a ~1us atomic barrier. Counter is a persistent __device__ global
// (NOT workspace — workspace is poisoned each iter); each launch adds
// exactly 256 so ticket base is always a multiple of 256 (replay-safe).
//
// Index algebra (harness-verified R0/R3/R4/R6/R8):
//   e[b,hp,i,j] = lrelu_0.2( f1flat[hp*256+i] + f2flat[(i&3)*256+j] ), flat=n*4+hh
//   f{1,2}flat[n*4+hh] = h[b,n,:].Wa{1,2}[:,hh], Wa{s}[k][hh]=sum_d W[k,hh*64+d]*a[s*64+d]
//   att = softmax_j(adj==0 ? -inf : e);  out = (attU @ Wh[:,hp*64:+64]) / rowsum

typedef __attribute__((ext_vector_type(8))) short bf16x8;
typedef __attribute__((ext_vector_type(4))) float f32x4;

__device__ unsigned g_ctr = 0;   // persistent across launches/replays

__device__ __forceinline__ short bf1(float x) {
  unsigned u = __builtin_bit_cast(unsigned, x);
  u = (u + 0x7FFFu + ((u >> 16) & 1u)) >> 16;        // RNE, harness-verified
  return (short)u;
}
__device__ __forceinline__ bf16x8 pack8(float4 a, float4 b) {
  bf16x8 r;
  r[0]=bf1(a.x); r[1]=bf1(a.y); r[2]=bf1(a.z); r[3]=bf1(a.w);
  r[4]=bf1(b.x); r[5]=bf1(b.y); r[6]=bf1(b.z); r[7]=bf1(b.w);
  return r;
}

__global__ __launch_bounds__(256) void gat_fused(
    const float* __restrict__ h, const float* __restrict__ W,
    const float* __restrict__ a, const int* __restrict__ adj,
    short* __restrict__ WhT, float* __restrict__ f1g, float* __restrict__ f2g,
    float* __restrict__ out)
{
  const int tid  = threadIdx.x;
  const int lane = tid & 63;
  const int quad = lane >> 4, col = lane & 15;
  const int wv   = tid >> 6;                       // 0..3
  const int blk  = blockIdx.x;
  const int ms = blk & 15, nt = (blk >> 4) & 3, b = blk >> 6;
  // phase 2 aliases: it = ms, hp = nt
  const int i0 = ms * 16;

  __shared__ short WbT[64][136];     // bf16 W[:, nt*64:+64]^T : [c][k]
  __shared__ short WaT16[16][136];   // rows 0=Wa1(head nt), 1=Wa2, 2..15 zero
  __shared__ short attb[16][264];    // phase 2: bf16 unnormalized softmax rows

  // ---- prefetch phase-2 adj rows into registers (cold HBM, hides under P1) -
  int4 adjv[4];
#pragma unroll
  for (int rq = 0; rq < 4; rq++)
    adjv[rq] = *(const int4*)(adj + (b*256 + i0 + wv*4 + rq)*256 + lane*4);

  // ================= phase 1 (R8-verified prep) ============================
  {
    // ---- issue W-slice + h loads ----------------------------------------
    float4 wl[8];
#pragma unroll
    for (int q = 0; q < 8; q++) {
      const int idx = q * 256 + tid;               // 2048 float4 of W slice
      const int k = idx >> 4, c4 = idx & 15;
      wl[q] = *(const float4*)(W + k * 256 + nt * 64 + c4 * 4);
    }
    const float* hrow = h + (b*256 + ms*16 + col) * 128 + quad*8;
    float4 hv[8];
#pragma unroll
    for (int kk = 0; kk < 4; kk++) {
      hv[2*kk]   = *(const float4*)(hrow + kk*32);
      hv[2*kk+1] = *(const float4*)(hrow + kk*32 + 4);
    }

    // ---- Wa fold (f32 W . a), thread t -> (k=t>>1, s=t&1) -----------------
    {
      const int k = tid >> 1, s = tid & 1;
      const float4* wr = (const float4*)(W + k * 256 + nt * 64);
      const float4* av = (const float4*)(a + s * 64);
      float sacc = 0.f;
#pragma unroll
      for (int d4 = 0; d4 < 16; d4++) {
        float4 x = wr[d4]; float4 y = av[d4];
        sacc += x.x*y.x + x.y*y.y + x.z*y.z + x.w*y.w;
      }
      WaT16[s][k] = bf1(sacc);
      int* zp = (int*)&WaT16[2][0];                // zero rows 2..15
      for (int t = tid; t < 952; t += 256) zp[t] = 0;
    }

    // ---- stage WbT --------------------------------------------------------
#pragma unroll
    for (int q = 0; q < 8; q++) {
      const int idx = q * 256 + tid;
      const int k = idx >> 4, c4 = idx & 15;
      WbT[c4*4 + 0][k] = bf1(wl[q].x);
      WbT[c4*4 + 1][k] = bf1(wl[q].y);
      WbT[c4*4 + 2][k] = bf1(wl[q].z);
      WbT[c4*4 + 3][k] = bf1(wl[q].w);
    }
    __syncthreads();

    // ---- A-fragments (shared by Wh-MFMA and f-MFMA) -----------------------
    bf16x8 afr[4];
#pragma unroll
    for (int kk = 0; kk < 4; kk++) afr[kk] = pack8(hv[2*kk], hv[2*kk+1]);

    // ---- Wh tile MFMA (K=128), wave wv = col-tile -------------------------
    f32x4 acc = {0.f, 0.f, 0.f, 0.f};
#pragma unroll
    for (int kk = 0; kk < 4; kk++) {
      bf16x8 bw = *(const bf16x8*)&WbT[wv*16 + col][kk*32 + quad*8];
      acc = __builtin_amdgcn_mfma_f32_16x16x32_bf16(afr[kk], bw, acc, 0, 0, 0);
    }
    {
      const int dcol = nt*64 + wv*16 + col;
      const int n0   = ms*16 + quad*4;
      int2 pk;
      pk.x = (int)((unsigned)(unsigned short)bf1(acc[0]) |
                   ((unsigned)(unsigned short)bf1(acc[1]) << 16));
      pk.y = (int)((unsigned)(unsigned short)bf1(acc[2]) |
                   ((unsigned)(unsigned short)bf1(acc[3]) << 16));
      *(int2*)(WhT + b*65536 + dcol*256 + n0) = pk;
    }

    // ---- f-MFMA (wave 0): C[row][0]=f1, C[row][1]=f2 ----------------------
    if (wv == 0) {
      f32x4 accF = {0.f, 0.f, 0.f, 0.f};
#pragma unroll
      for (int kk = 0; kk < 4; kk++) {
        bf16x8 bw = *(const bf16x8*)&WaT16[col][kk*32 + quad*8];
        accF = __builtin_amdgcn_mfma_f32_16x16x32_bf16(afr[kk], bw, accF, 0, 0, 0);
      }
      if (col < 2) {
        float* dst = (col == 0) ? f1g : f2g;
#pragma unroll
        for (int r = 0; r < 4; r++)
          dst[b*1024 + (ms*16 + quad*4 + r)*4 + nt] = accF[r];
      }
    }
  }

  // ================= device-scope ticket barrier ===========================
  __threadfence();                                 // make this block's writes agent-visible
  __syncthreads();                                 // all waves' stores issued + fenced
  if (tid == 0) {
    const unsigned t    = __hip_atomic_fetch_add(&g_ctr, 1u, __ATOMIC_ACQ_REL,
                                                 __HIP_MEMORY_SCOPE_AGENT);
    const unsigned base = t & ~255u;               // launch adds exactly 256
    while (__hip_atomic_load(&g_ctr, __ATOMIC_ACQUIRE,
                             __HIP_MEMORY_SCOPE_AGENT) - base < 256u) {
      __builtin_amdgcn_s_sleep(1);
    }
  }
  __syncthreads();
  // per-thread acquire so every wave's subsequent loads see remote writes
  (void)__hip_atomic_load(&g_ctr, __ATOMIC_ACQUIRE, __HIP_MEMORY_SCOPE_AGENT);

  // ================= phase 2 (R6-verified attn; hp=nt, it=ms) ==============
  {
    const int hp = nt;

    // ---- loads (all post-barrier; mostly L2/L3-resident now) --------------
    bf16x8 bv[8];                                  // WhT B-frags (K=256)
    const short* bp = WhT + b*65536 + (hp*64 + wv*16 + col)*256 + quad*8;
#pragma unroll
    for (int kk = 0; kk < 8; kk++) bv[kk] = *(const bf16x8*)(bp + kk*32);

    float4 f2v[4]; float f1s[4];
#pragma unroll
    for (int rq = 0; rq < 4; rq++) {
      const int i = i0 + wv*4 + rq;                // i & 3 == rq
      f2v[rq] = *(const float4*)(f2g + b*1024 + rq*256 + lane*4);
      f1s[rq] = f1g[b*1024 + hp*256 + i];
    }

    // ---- softmax numerators (no reductions; adj from pre-barrier regs) ----
#pragma unroll
    for (int rq = 0; rq < 4; rq++) {
      const int rr = wv*4 + rq;
      const float s1v = f1s[rq];
      float e0 = s1v + f2v[rq].x, e1 = s1v + f2v[rq].y;
      float e2 = s1v + f2v[rq].z, e3 = s1v + f2v[rq].w;
      e0 = e0 > 0.f ? e0 : 0.2f*e0;  e1 = e1 > 0.f ? e1 : 0.2f*e1;
      e2 = e2 > 0.f ? e2 : 0.2f*e2;  e3 = e3 > 0.f ? e3 : 0.2f*e3;
      e0 = adjv[rq].x ? e0 : -1e30f;  e1 = adjv[rq].y ? e1 : -1e30f;
      e2 = adjv[rq].z ? e2 : -1e30f;  e3 = adjv[rq].w ? e3 : -1e30f;
      float x0 = __expf(e0), x1 = __expf(e1);
      float x2 = __expf(e2), x3 = __expf(e3);
      int2 pk2;
      pk2.x = (int)((unsigned)(unsigned short)bf1(x0) |
                    ((unsigned)(unsigned short)bf1(x1) << 16));
      pk2.y = (int)((unsigned)(unsigned short)bf1(x2) |
                    ((unsigned)(unsigned short)bf1(x3) << 16));
      *(int2*)&attb[rr][lane*4] = pk2;
    }
    __syncthreads();

    // ---- GEMM + MFMA row-sums ---------------------------------------------
    bf16x8 af[8];
#pragma unroll
    for (int kk = 0; kk < 8; kk++)
      af[kk] = *(const bf16x8*)&attb[col][kk*32 + quad*8];

    bf16x8 ones;
#pragma unroll
    for (int j = 0; j < 8; j++) ones[j] = (short)0x3F80;   // bf16 1.0

    f32x4 acc0 = {0.f,0.f,0.f,0.f}, acc1 = {0.f,0.f,0.f,0.f};
    f32x4 sum0 = {0.f,0.f,0.f,0.f}, sum1 = {0.f,0.f,0.f,0.f};
#pragma unroll
    for (int kk = 0; kk < 4; kk++) {
      acc0 = __builtin_amdgcn_mfma_f32_16x16x32_bf16(af[kk],   bv[kk],   acc0, 0, 0, 0);
      acc1 = __builtin_amdgcn_mfma_f32_16x16x32_bf16(af[kk+4], bv[kk+4], acc1, 0, 0, 0);
      sum0 = __builtin_amdgcn_mfma_f32_16x16x32_bf16(af[kk],   ones,     sum0, 0, 0, 0);
      sum1 = __builtin_amdgcn_mfma_f32_16x16x32_bf16(af[kk+4], ones,     sum1, 0, 0, 0);
    }
#pragma unroll
    for (int r = 0; r < 4; r++) {
      const int m = quad*4 + r;                    // row within 16-tile
      out[(b*256 + i0 + m)*256 + hp*64 + wv*16 + col] =
          (acc0[r] + acc1[r]) / (sum0[r] + sum1[r]);
    }
  }
}

extern "C" void kernel_launch(void* const* d_in, const int* in_sizes, int n_in,
                              void* d_out, int out_size, void* d_ws, size_t ws_size,
                              hipStream_t stream) {
  const float* h   = (const float*)d_in[0];   // [4,256,128]
  const int*   adj = (const int*)d_in[1];     // [4,256,256]
  const float* W   = (const float*)d_in[2];   // [128,256]
  const float* a   = (const float*)d_in[3];   // [128,1]
  float* out = (float*)d_out;                 // [4,256,256]

  short* WhT = (short*)d_ws;                  // [4][256 dcol][256 n] bf16, 512 KB
  float* f1g = (float*)((char*)d_ws + 4*256*256*2);   // [4][1024] f32
  float* f2g = f1g + 4*1024;                           // [4][1024] f32

  gat_fused<<<256, 256, 0, stream>>>(h, W, a, adj, WhT, f1g, f2g, out);
}